// Round 15
// baseline (976.293 us; speedup 1.0000x reference)
//
#include <hip/hip_runtime.h>
#include <math.h>

#define EPS 1e-3f
#define H 256
#define QDIM 6
#define NTRI 10
#define EPB 16
#define PADH 260   // fp32 row pad: 1040B rows, 16B-aligned, 2-way-free banks

typedef _Float16 half8 __attribute__((ext_vector_type(8)));
typedef float floatx4 __attribute__((ext_vector_type(4)));

#define WSZ (H * H)

__device__ __forceinline__ float softplusf(float x) {
    if (x > 20.f) return x;
    return log1pf(expf(x));
}

__device__ __forceinline__ void split8(const float* __restrict__ p, half8& hi, half8& lo) {
    #pragma unroll
    for (int i = 0; i < 8; i++) {
        float a = p[i];
        _Float16 h = (_Float16)a;
        hi[i] = h;
        lo[i] = (_Float16)(a - (float)h);
    }
}

#define MFMA(A, B, C) __builtin_amdgcn_mfma_f32_16x16x32_f16((A), (B), (C), 0, 0, 0)

// 16-row A (fp32 LDS, split on the fly) x 64-col B (pre-split fp16 hi/lo),
// 2-slot register double-buffer over flattened (kc,t). acc = 16 regs only.
__device__ __forceinline__ void gemm16(
    const float (*__restrict__ Arows)[PADH],
    const _Float16* __restrict__ Bhi, const _Float16* __restrict__ Blo,
    int wid, int fr, int kb, floatx4 (&acc)[4])
{
    half8 bh[2], bl[2];
    {
        const int off = ((wid * 4 + 0) * 16 + fr) * H + kb;
        bh[0] = *(const half8*)&Bhi[off];
        bl[0] = *(const half8*)&Blo[off];
    }
    #pragma unroll
    for (int kc = 0; kc < 8; kc++) {
        half8 ah, al;
        split8(&Arows[fr][kc * 32 + kb], ah, al);
        #pragma unroll
        for (int t = 0; t < 4; t++) {
            const int cur = (kc * 4 + t) & 1;
            const int nxt = cur ^ 1;
            const int nkc = (t < 3) ? kc : kc + 1;
            const int nt  = (t < 3) ? t + 1 : 0;
            if (nkc < 8) {
                const int off = ((wid * 4 + nt) * 16 + fr) * H + nkc * 32 + kb;
                bh[nxt] = *(const half8*)&Bhi[off];
                bl[nxt] = *(const half8*)&Blo[off];
            }
            acc[t] = MFMA(ah, bh[cur], acc[t]);
            acc[t] = MFMA(ah, bl[cur], acc[t]);
            acc[t] = MFMA(al, bh[cur], acc[t]);
        }
    }
}

// ---- prep: pre-split weights to fp16 hi/lo in both layouts; transpose mW2 ----
__global__ __launch_bounds__(256) void prep_kernel(
    const float* __restrict__ mW1, const float* __restrict__ vW1,
    const float* __restrict__ mW2, void* __restrict__ ws)
{
    _Float16* h = (_Float16*)ws;
    float* W2t = (float*)(h + 8 * WSZ);
    const int k = blockIdx.x;
    const int j = threadIdx.x;
    {
        float a = mW1[k * H + j];
        _Float16 hi = (_Float16)a;
        _Float16 lo = (_Float16)(a - (float)hi);
        h[0 * WSZ + j * H + k] = hi;   // W1t_hi
        h[1 * WSZ + j * H + k] = lo;   // W1t_lo
        h[2 * WSZ + k * H + j] = hi;   // W1m_hi
        h[3 * WSZ + k * H + j] = lo;   // W1m_lo
    }
    {
        float a = vW1[k * H + j];
        _Float16 hi = (_Float16)a;
        _Float16 lo = (_Float16)(a - (float)hi);
        h[4 * WSZ + j * H + k] = hi;   // V1t_hi
        h[5 * WSZ + j * H + k] = lo;   // V1t_lo
        h[6 * WSZ + k * H + j] = hi;   // V1m_hi
        h[7 * WSZ + k * H + j] = lo;   // V1m_lo
    }
    if (k < NTRI) W2t[k * H + j] = mW2[j * NTRI + k];
}

__global__ __launch_bounds__(256) void lnn_kernel(
    const float* __restrict__ x,
    const float* __restrict__ mW0, const float* __restrict__ mb0,
    const float* __restrict__ mb1,
    const float* __restrict__ mW2, const float* __restrict__ mb2,
    const float* __restrict__ vW0, const float* __restrict__ vb0,
    const float* __restrict__ vb1,
    const float* __restrict__ vW2,
    const void* __restrict__ ws,
    float* __restrict__ out, int n)
{
    const _Float16* wsh = (const _Float16*)ws;
    const _Float16* W1t_hi = wsh + 0 * WSZ;
    const _Float16* W1t_lo = wsh + 1 * WSZ;
    const _Float16* W1m_hi = wsh + 2 * WSZ;
    const _Float16* W1m_lo = wsh + 3 * WSZ;
    const _Float16* V1t_hi = wsh + 4 * WSZ;
    const _Float16* V1t_lo = wsh + 5 * WSZ;
    const _Float16* V1m_hi = wsh + 6 * WSZ;
    const _Float16* V1m_lo = wsh + 7 * WSZ;
    const float*    W2t    = (const float*)(wsh + 8 * WSZ);

    __shared__ float s_qd[EPB][10];
    __shared__ float s_h1[EPB][PADH];        // g1, then h1
    __shared__ float s_h2[EPB][PADH];        // gg2, then h2
    __shared__ float s_sd[32][PADH];         // Eh1 seeds (one 8-element stage)
    __shared__ float s_ent[EPB][NTRI];
    __shared__ float s_entbar[EPB][4][NTRI];
    __shared__ float s_Jp[4][EPB][4][6];     // [wid][e][s][i]
    __shared__ float s_dVp[4][EPB][6];       // [wid][e][i]
    __shared__ float s_L[EPB][16];

    const int tid = threadIdx.x;
    const int e0 = blockIdx.x * EPB;
    const int lane = tid & 63;
    const int wid = tid >> 6;
    const int fr = lane & 15;
    const int fg = lane >> 4;
    const int kb = fg * 8;

    // ---- load q, dq ----
    if (tid < EPB * 10) {
        int e = tid / 10, c = tid % 10;
        int ge = e0 + e;
        s_qd[e][c] = (ge < n) ? x[ge * 10 + c] : 0.f;
    }
    __syncthreads();

    // ================= V chain =================
    // ---- V layer 0: g1 ----
    {
        const int j = tid;
        float w[QDIM];
        #pragma unroll
        for (int i = 0; i < QDIM; i++) w[i] = vW0[i * H + j];
        const float b = vb0[j];
        #pragma unroll 4
        for (int e = 0; e < EPB; e++) {
            float z = b;
            #pragma unroll
            for (int i = 0; i < QDIM; i++) z += s_qd[e][i] * w[i];
            s_h1[e][j] = tanhf(z);
        }
    }
    __syncthreads();

    // ---- V layer 1 MFMA: gg2 = (1-g2^2)*vW2[j] -> s_h2 ----
    {
        floatx4 acc[4];
        #pragma unroll
        for (int t = 0; t < 4; t++) acc[t] = (floatx4)(0.f);
        gemm16(s_h1, V1t_hi, V1t_lo, wid, fr, kb, acc);
        #pragma unroll
        for (int t = 0; t < 4; t++) {
            const int j = (wid * 4 + t) * 16 + fr;
            const float b = vb1[j];
            const float w2 = vW2[j];
            #pragma unroll
            for (int rr = 0; rr < 4; rr++) {
                const int e = fg * 4 + rr;
                const float g2 = tanhf(acc[t][rr] + b);
                s_h2[e][j] = (1.f - g2 * g2) * w2;
            }
        }
    }
    __syncthreads();

    // ---- gg1 MFMA + fused dV ----
    {
        floatx4 acc[4];
        #pragma unroll
        for (int t = 0; t < 4; t++) acc[t] = (floatx4)(0.f);
        gemm16(s_h2, V1m_hi, V1m_lo, wid, fr, kb, acc);

        float part[4][6];
        #pragma unroll
        for (int rr = 0; rr < 4; rr++)
            #pragma unroll
            for (int i = 0; i < 6; i++) part[rr][i] = 0.f;
        #pragma unroll
        for (int t = 0; t < 4; t++) {
            const int outk = (wid * 4 + t) * 16 + fr;
            float w0[6];
            #pragma unroll
            for (int i = 0; i < 6; i++) w0[i] = vW0[i * H + outk];
            #pragma unroll
            for (int rr = 0; rr < 4; rr++) {
                const float g = s_h1[fg * 4 + rr][outk];
                const float t1 = 1.f - g * g;
                const float v = acc[t][rr] * t1;
                #pragma unroll
                for (int i = 0; i < 6; i++) part[rr][i] = fmaf(v, w0[i], part[rr][i]);
            }
        }
        #pragma unroll
        for (int m = 1; m < 16; m <<= 1)
            #pragma unroll
            for (int rr = 0; rr < 4; rr++)
                #pragma unroll
                for (int i = 0; i < 6; i++)
                    part[rr][i] += __shfl_xor(part[rr][i], m);
        if (fr == 0) {
            #pragma unroll
            for (int rr = 0; rr < 4; rr++)
                #pragma unroll
                for (int i = 0; i < 6; i++)
                    s_dVp[wid][fg * 4 + rr][i] = part[rr][i];
        }
    }
    __syncthreads();

    // ================= mass chain =================
    // ---- mass layer 0: h1 (overwrite g1) ----
    {
        const int j = tid;
        float w[QDIM];
        #pragma unroll
        for (int i = 0; i < QDIM; i++) w[i] = mW0[i * H + j];
        const float b = mb0[j];
        #pragma unroll 4
        for (int e = 0; e < EPB; e++) {
            float z = b;
            #pragma unroll
            for (int i = 0; i < QDIM; i++) z += s_qd[e][i] * w[i];
            s_h1[e][j] = tanhf(z);
        }
    }
    __syncthreads();

    // ---- mass layer 1 MFMA: h2 = tanh(h1 @ W1 + b1) -> s_h2 ----
    {
        floatx4 acc[4];
        #pragma unroll
        for (int t = 0; t < 4; t++) acc[t] = (floatx4)(0.f);
        gemm16(s_h1, W1t_hi, W1t_lo, wid, fr, kb, acc);
        #pragma unroll
        for (int t = 0; t < 4; t++) {
            const int j = (wid * 4 + t) * 16 + fr;
            const float b = mb1[j];
            #pragma unroll
            for (int rr = 0; rr < 4; rr++)
                s_h2[fg * 4 + rr][j] = tanhf(acc[t][rr] + b);
        }
    }
    __syncthreads();

    // ---- ent = h2 @ W2 + b2 ----
    if (tid < EPB * NTRI) {
        int e = tid / NTRI, m = tid % NTRI;
        float acc = mb2[m];
        const float* wrow = &W2t[m * H];
        for (int j = 0; j < H; j += 4) {
            const float2 h0 = *(const float2*)&s_h2[e][j];
            const float2 h1 = *(const float2*)&s_h2[e][j + 2];
            const float4 wv = *(const float4*)&wrow[j];
            acc += h0.x * wv.x + h0.y * wv.y + h1.x * wv.z + h1.y * wv.w;
        }
        s_ent[e][m] = acc;
    }
    __syncthreads();

    // ---- per-element: L (to LDS), a = L^T dq, ent_bar seeds ----
    if (tid < EPB) {
        const int e = tid;
        const int ti[10] = {0,1,1,2,2,2,3,3,3,3};
        const int tj[10] = {0,0,1,0,1,2,0,1,2,3};
        float L[4][4];
        #pragma unroll
        for (int r = 0; r < 4; r++)
            #pragma unroll
            for (int c = 0; c < 4; c++) L[r][c] = 0.f;
        float sig[10];
        #pragma unroll
        for (int m = 0; m < 10; m++) {
            float v = s_ent[e][m];
            if (ti[m] == tj[m]) {
                sig[m] = 1.f / (1.f + expf(-v));
                L[ti[m]][tj[m]] = softplusf(v);
            } else {
                sig[m] = 1.f;
                L[ti[m]][tj[m]] = v;
            }
        }
        #pragma unroll
        for (int r = 0; r < 4; r++)
            #pragma unroll
            for (int c = 0; c < 4; c++) s_L[e][r * 4 + c] = L[r][c];
        float dq[4];
        #pragma unroll
        for (int r = 0; r < 4; r++) dq[r] = s_qd[e][6 + r];
        float a[4];
        #pragma unroll
        for (int c = 0; c < 4; c++) {
            float s = 0.f;
            #pragma unroll
            for (int r = 0; r < 4; r++) s += L[r][c] * dq[r];
            a[c] = s;
        }
        #pragma unroll
        for (int s = 0; s < 4; s++) {
            #pragma unroll
            for (int m = 0; m < 10; m++) {
                float v = ((ti[m] == s) ? a[tj[m]] : 0.f) + dq[ti[m]] * L[s][tj[m]];
                s_entbar[e][s][m] = v * sig[m];
            }
        }
    }
    __syncthreads();

    // ---- Eh1 in 2 stages of 8 elements; each stage = 2 gemm16 halves ----
    for (int hstage = 0; hstage < 2; hstage++) {
        // seeds: rows el*4+s for e = hstage*8+el
        {
            const int j = tid;
            float w2row[NTRI];
            #pragma unroll
            for (int m = 0; m < NTRI; m++) w2row[m] = mW2[j * NTRI + m];
            #pragma unroll 2
            for (int el = 0; el < 8; el++) {
                const int e = hstage * 8 + el;
                const float h = s_h2[e][j];
                const float t2 = 1.f - h * h;
                #pragma unroll
                for (int s = 0; s < 4; s++) {
                    float acc = 0.f;
                    #pragma unroll
                    for (int m = 0; m < NTRI; m++) acc += w2row[m] * s_entbar[e][s][m];
                    s_sd[el * 4 + s][j] = acc * t2;
                }
            }
        }
        __syncthreads();

        // two 16-row halves, each: gemm16 + immediate fused-J epilogue
        #pragma unroll 1
        for (int half = 0; half < 2; half++) {
            floatx4 acc[4];
            #pragma unroll
            for (int t = 0; t < 4; t++) acc[t] = (floatx4)(0.f);
            gemm16(s_sd + half * 16, W1m_hi, W1m_lo, wid, fr, kb, acc);

            const int e = hstage * 8 + half * 4 + fg;
            float part[4][6];
            #pragma unroll
            for (int rr = 0; rr < 4; rr++)
                #pragma unroll
                for (int i = 0; i < 6; i++) part[rr][i] = 0.f;
            #pragma unroll
            for (int t = 0; t < 4; t++) {
                const int outk = (wid * 4 + t) * 16 + fr;
                float w0[6];
                #pragma unroll
                for (int i = 0; i < 6; i++) w0[i] = mW0[i * H + outk];
                const float h = s_h1[e][outk];
                const float t1 = 1.f - h * h;
                #pragma unroll
                for (int rr = 0; rr < 4; rr++) {
                    const float v = acc[t][rr] * t1;
                    #pragma unroll
                    for (int i = 0; i < 6; i++) part[rr][i] = fmaf(v, w0[i], part[rr][i]);
                }
            }
            #pragma unroll
            for (int m = 1; m < 16; m <<= 1)
                #pragma unroll
                for (int rr = 0; rr < 4; rr++)
                    #pragma unroll
                    for (int i = 0; i < 6; i++)
                        part[rr][i] += __shfl_xor(part[rr][i], m);
            if (fr == 0) {
                #pragma unroll
                for (int rr = 0; rr < 4; rr++)
                    #pragma unroll
                    for (int i = 0; i < 6; i++)
                        s_Jp[wid][e][rr][i] = part[rr][i];
            }
        }
        __syncthreads();
    }

    // ---- finalize per element ----
    if (tid < EPB && (e0 + tid) < n) {
        const int e = tid;
        float q[6], dq[4];
        #pragma unroll
        for (int i = 0; i < 6; i++) q[i] = s_qd[e][i];
        #pragma unroll
        for (int r = 0; r < 4; r++) dq[r] = s_qd[e][6 + r];
        const float x1a = q[2], x1b = q[3], x2a = q[4], x2b = q[5];
        float J[4][6];
        #pragma unroll
        for (int r = 0; r < 4; r++)
            #pragma unroll
            for (int i = 0; i < 6; i++)
                J[r][i] = s_Jp[0][e][r][i] + s_Jp[1][e][r][i] + s_Jp[2][e][r][i] + s_Jp[3][e][r][i];
        float dV[6];
        #pragma unroll
        for (int i = 0; i < 6; i++)
            dV[i] = s_dVp[0][e][i] + s_dVp[1][e][i] + s_dVp[2][e][i] + s_dVp[3][e][i];

        float G[4][4];
        #pragma unroll
        for (int r = 0; r < 4; r++) {
            G[r][0] = J[r][0];
            G[r][1] = J[r][1];
            G[r][2] = -x2a * J[r][2] + x1a * J[r][4];
            G[r][3] = -x2b * J[r][3] + x1b * J[r][5];
        }
        float gL[6];
        #pragma unroll
        for (int i = 0; i < 6; i++) {
            float s = 0.f;
            #pragma unroll
            for (int r = 0; r < 4; r++) s += dq[r] * J[r][i];
            gL[i] = 0.5f * s - dV[i];
        }
        float dLdq[4];
        dLdq[0] = gL[0];
        dLdq[1] = gL[1];
        dLdq[2] = -x2a * gL[2] + x1a * gL[4];
        dLdq[3] = -x2b * gL[3] + x1b * gL[5];
        float b[4];
        #pragma unroll
        for (int r = 0; r < 4; r++) {
            float s = 0.f;
            #pragma unroll
            for (int c = 0; c < 4; c++) s += G[r][c] * dq[c];
            b[r] = dLdq[r] - s;
        }
        float M[4][4];
        #pragma unroll
        for (int r = 0; r < 4; r++)
            #pragma unroll
            for (int c = 0; c <= r; c++) {
                float s = 0.f;
                #pragma unroll
                for (int k = 0; k < 4; k++) s += s_L[e][r * 4 + k] * s_L[e][c * 4 + k];
                M[r][c] = s;
            }
        #pragma unroll
        for (int r = 0; r < 4; r++) M[r][r] += EPS;
        float C00 = sqrtf(M[0][0]);
        float C10 = M[1][0] / C00, C20 = M[2][0] / C00, C30 = M[3][0] / C00;
        float C11 = sqrtf(M[1][1] - C10 * C10);
        float C21 = (M[2][1] - C20 * C10) / C11;
        float C31 = (M[3][1] - C30 * C10) / C11;
        float C22 = sqrtf(M[2][2] - C20 * C20 - C21 * C21);
        float C32 = (M[3][2] - C30 * C20 - C31 * C21) / C22;
        float C33 = sqrtf(M[3][3] - C30 * C30 - C31 * C31 - C32 * C32);
        float y0 = b[0] / C00;
        float y1 = (b[1] - C10 * y0) / C11;
        float y2 = (b[2] - C20 * y0 - C21 * y1) / C22;
        float y3 = (b[3] - C30 * y0 - C31 * y1 - C32 * y2) / C33;
        float d3 = y3 / C33;
        float d2 = (y2 - C32 * d3) / C22;
        float d1 = (y1 - C21 * d2 - C31 * d3) / C11;
        float d0 = (y0 - C10 * d1 - C20 * d2 - C30 * d3) / C00;

        float* o = &out[(e0 + e) * 10];
        o[0] = dq[0];
        o[1] = dq[1];
        o[2] = -x2a * dq[2];
        o[3] = -x2b * dq[3];
        o[4] = x1a * dq[2];
        o[5] = x1b * dq[3];
        o[6] = d0; o[7] = d1; o[8] = d2; o[9] = d3;
    }
}

extern "C" void kernel_launch(void* const* d_in, const int* in_sizes, int n_in,
                              void* d_out, int out_size, void* d_ws, size_t ws_size,
                              hipStream_t stream) {
    const float* x   = (const float*)d_in[0];
    const float* mW0 = (const float*)d_in[1];
    const float* mb0 = (const float*)d_in[2];
    const float* mW1 = (const float*)d_in[3];
    const float* mb1 = (const float*)d_in[4];
    const float* mW2 = (const float*)d_in[5];
    const float* mb2 = (const float*)d_in[6];
    const float* vW0 = (const float*)d_in[7];
    const float* vb0 = (const float*)d_in[8];
    const float* vW1 = (const float*)d_in[9];
    const float* vb1 = (const float*)d_in[10];
    const float* vW2 = (const float*)d_in[11];
    float* out = (float*)d_out;
    const int n = in_sizes[0] / 10;

    prep_kernel<<<H, H, 0, stream>>>(mW1, vW1, mW2, d_ws);

    const int blocks = (n + EPB - 1) / EPB;
    lnn_kernel<<<blocks, 256, 0, stream>>>(x, mW0, mb0, mb1, mW2, mb2,
                                           vW0, vb0, vb1, vW2,
                                           d_ws, out, n);
}

// Round 16
// 791.030 us; speedup vs baseline: 1.2342x; 1.2342x over previous
//
#include <hip/hip_runtime.h>
#include <math.h>

#define EPS 1e-3f
#define H 256
#define QDIM 6
#define NTRI 10
#define EPB 16
#define PADH 260   // fp32 row pad

typedef _Float16 half8 __attribute__((ext_vector_type(8)));
typedef float floatx4 __attribute__((ext_vector_type(4)));

#define WSZ (H * H)

__device__ __forceinline__ float softplusf(float x) {
    if (x > 20.f) return x;
    return log1pf(expf(x));
}

__device__ __forceinline__ void split8(const float* __restrict__ p, half8& hi, half8& lo) {
    #pragma unroll
    for (int i = 0; i < 8; i++) {
        float a = p[i];
        _Float16 h = (_Float16)a;
        hi[i] = h;
        lo[i] = (_Float16)(a - (float)h);
    }
}

#define MFMA(A, B, C) __builtin_amdgcn_mfma_f32_16x16x32_f16((A), (B), (C), 0, 0, 0)

// 16-row A x 64-col B, 2-slot register double-buffer
__device__ __forceinline__ void gemm16(
    const float (*__restrict__ Arows)[PADH],
    const _Float16* __restrict__ Bhi, const _Float16* __restrict__ Blo,
    int wid, int fr, int kb, floatx4 (&acc)[4])
{
    half8 bh[2], bl[2];
    {
        const int off = ((wid * 4 + 0) * 16 + fr) * H + kb;
        bh[0] = *(const half8*)&Bhi[off];
        bl[0] = *(const half8*)&Blo[off];
    }
    #pragma unroll
    for (int kc = 0; kc < 8; kc++) {
        half8 ah, al;
        split8(&Arows[fr][kc * 32 + kb], ah, al);
        #pragma unroll
        for (int t = 0; t < 4; t++) {
            const int cur = (kc * 4 + t) & 1;
            const int nxt = cur ^ 1;
            const int nkc = (t < 3) ? kc : kc + 1;
            const int nt  = (t < 3) ? t + 1 : 0;
            if (nkc < 8) {
                const int off = ((wid * 4 + nt) * 16 + fr) * H + nkc * 32 + kb;
                bh[nxt] = *(const half8*)&Bhi[off];
                bl[nxt] = *(const half8*)&Blo[off];
            }
            acc[t] = MFMA(ah, bh[cur], acc[t]);
            acc[t] = MFMA(ah, bl[cur], acc[t]);
            acc[t] = MFMA(al, bh[cur], acc[t]);
        }
    }
}

// 32-row A variant, acc[4][2]
__device__ __forceinline__ void gemm32(
    const float (*__restrict__ Arows)[PADH],
    const _Float16* __restrict__ Bhi, const _Float16* __restrict__ Blo,
    int wid, int fr, int kb, floatx4 (&acc)[4][2])
{
    half8 bh[2], bl[2];
    {
        const int off = ((wid * 4 + 0) * 16 + fr) * H + kb;
        bh[0] = *(const half8*)&Bhi[off];
        bl[0] = *(const half8*)&Blo[off];
    }
    #pragma unroll
    for (int kc = 0; kc < 8; kc++) {
        half8 ah[2], al[2];
        #pragma unroll
        for (int mt = 0; mt < 2; mt++)
            split8(&Arows[mt * 16 + fr][kc * 32 + kb], ah[mt], al[mt]);
        #pragma unroll
        for (int t = 0; t < 4; t++) {
            const int cur = (kc * 4 + t) & 1;
            const int nxt = cur ^ 1;
            const int nkc = (t < 3) ? kc : kc + 1;
            const int nt  = (t < 3) ? t + 1 : 0;
            if (nkc < 8) {
                const int off = ((wid * 4 + nt) * 16 + fr) * H + nkc * 32 + kb;
                bh[nxt] = *(const half8*)&Bhi[off];
                bl[nxt] = *(const half8*)&Blo[off];
            }
            #pragma unroll
            for (int mt = 0; mt < 2; mt++) {
                acc[t][mt] = MFMA(ah[mt], bh[cur], acc[t][mt]);
                acc[t][mt] = MFMA(ah[mt], bl[cur], acc[t][mt]);
                acc[t][mt] = MFMA(al[mt], bh[cur], acc[t][mt]);
            }
        }
    }
}

// ---------- noinline phase functions: isolate register allocation ----------

// layer-0: out = tanh(q @ W0 + b0), all 256 lanes
__device__ __noinline__ void phase_layer0(
    const float (*__restrict__ s_qd)[10],
    const float* __restrict__ W0, const float* __restrict__ b0,
    float (*__restrict__ Aout)[PADH], int tid)
{
    const int j = tid;
    float w[QDIM];
    #pragma unroll
    for (int i = 0; i < QDIM; i++) w[i] = W0[i * H + j];
    const float b = b0[j];
    #pragma unroll 4
    for (int e = 0; e < EPB; e++) {
        float z = b;
        #pragma unroll
        for (int i = 0; i < QDIM; i++) z += s_qd[e][i] * w[i];
        Aout[e][j] = tanhf(z);
    }
}

// forward layer-1: MFMA; epilogue tanh(+b) or gg2=(1-g2^2)*w2
__device__ __noinline__ void phase_fwd(
    const float (*__restrict__ Ain)[PADH],
    const _Float16* __restrict__ Bhi, const _Float16* __restrict__ Blo,
    const float* __restrict__ bias, const float* __restrict__ w2opt,
    float (*__restrict__ Aout)[PADH], int wid, int fr, int fg, int kb)
{
    floatx4 acc[4];
    #pragma unroll
    for (int t = 0; t < 4; t++) acc[t] = (floatx4)(0.f);
    gemm16(Ain, Bhi, Blo, wid, fr, kb, acc);
    #pragma unroll
    for (int t = 0; t < 4; t++) {
        const int j = (wid * 4 + t) * 16 + fr;
        const float b = bias[j];
        if (w2opt) {
            const float w2 = w2opt[j];
            #pragma unroll
            for (int rr = 0; rr < 4; rr++) {
                const float g2 = tanhf(acc[t][rr] + b);
                Aout[fg * 4 + rr][j] = (1.f - g2 * g2) * w2;
            }
        } else {
            #pragma unroll
            for (int rr = 0; rr < 4; rr++)
                Aout[fg * 4 + rr][j] = tanhf(acc[t][rr] + b);
        }
    }
}

// gg1 MFMA + fused dV reduce
__device__ __noinline__ void phase_bwd_dV(
    const float (*__restrict__ Ain)[PADH],
    const _Float16* __restrict__ Bhi, const _Float16* __restrict__ Blo,
    const float* __restrict__ vW0, const float (*__restrict__ g1)[PADH],
    float (*__restrict__ dVp)[EPB][6], int wid, int fr, int fg, int kb)
{
    floatx4 acc[4];
    #pragma unroll
    for (int t = 0; t < 4; t++) acc[t] = (floatx4)(0.f);
    gemm16(Ain, Bhi, Blo, wid, fr, kb, acc);

    float part[4][6];
    #pragma unroll
    for (int rr = 0; rr < 4; rr++)
        #pragma unroll
        for (int i = 0; i < 6; i++) part[rr][i] = 0.f;
    #pragma unroll
    for (int t = 0; t < 4; t++) {
        const int outk = (wid * 4 + t) * 16 + fr;
        float w0[6];
        #pragma unroll
        for (int i = 0; i < 6; i++) w0[i] = vW0[i * H + outk];
        #pragma unroll
        for (int rr = 0; rr < 4; rr++) {
            const float g = g1[fg * 4 + rr][outk];
            const float t1 = 1.f - g * g;
            const float v = acc[t][rr] * t1;
            #pragma unroll
            for (int i = 0; i < 6; i++) part[rr][i] = fmaf(v, w0[i], part[rr][i]);
        }
    }
    #pragma unroll
    for (int m = 1; m < 16; m <<= 1)
        #pragma unroll
        for (int rr = 0; rr < 4; rr++)
            #pragma unroll
            for (int i = 0; i < 6; i++)
                part[rr][i] += __shfl_xor(part[rr][i], m);
    if (fr == 0) {
        #pragma unroll
        for (int rr = 0; rr < 4; rr++)
            #pragma unroll
            for (int i = 0; i < 6; i++)
                dVp[wid][fg * 4 + rr][i] = part[rr][i];
    }
}

// Eh1 gemm32 + fused J reduce (one 8-element stage)
__device__ __noinline__ void phase_eh1(
    const float (*__restrict__ sd)[PADH],
    const _Float16* __restrict__ Bhi, const _Float16* __restrict__ Blo,
    const float* __restrict__ mW0, const float (*__restrict__ h1)[PADH],
    float (*__restrict__ Jp)[EPB][4][6], int hstage, int wid, int fr, int fg, int kb)
{
    floatx4 acc[4][2];
    #pragma unroll
    for (int t = 0; t < 4; t++)
        #pragma unroll
        for (int mt = 0; mt < 2; mt++) acc[t][mt] = (floatx4)(0.f);
    gemm32(sd, Bhi, Blo, wid, fr, kb, acc);

    #pragma unroll
    for (int mt = 0; mt < 2; mt++) {
        const int e = hstage * 8 + mt * 4 + fg;
        float part[4][6];
        #pragma unroll
        for (int rr = 0; rr < 4; rr++)
            #pragma unroll
            for (int i = 0; i < 6; i++) part[rr][i] = 0.f;
        #pragma unroll
        for (int t = 0; t < 4; t++) {
            const int outk = (wid * 4 + t) * 16 + fr;
            float w0[6];
            #pragma unroll
            for (int i = 0; i < 6; i++) w0[i] = mW0[i * H + outk];
            const float h = h1[e][outk];
            const float t1 = 1.f - h * h;
            #pragma unroll
            for (int rr = 0; rr < 4; rr++) {
                const float v = acc[t][mt][rr] * t1;
                #pragma unroll
                for (int i = 0; i < 6; i++) part[rr][i] = fmaf(v, w0[i], part[rr][i]);
            }
        }
        #pragma unroll
        for (int m = 1; m < 16; m <<= 1)
            #pragma unroll
            for (int rr = 0; rr < 4; rr++)
                #pragma unroll
                for (int i = 0; i < 6; i++)
                    part[rr][i] += __shfl_xor(part[rr][i], m);
        if (fr == 0) {
            #pragma unroll
            for (int rr = 0; rr < 4; rr++)
                #pragma unroll
                for (int i = 0; i < 6; i++)
                    Jp[wid][e][rr][i] = part[rr][i];
        }
    }
}

// ---- prep: pre-split weights to fp16 hi/lo in both layouts; transpose mW2 ----
__global__ __launch_bounds__(256) void prep_kernel(
    const float* __restrict__ mW1, const float* __restrict__ vW1,
    const float* __restrict__ mW2, void* __restrict__ ws)
{
    _Float16* h = (_Float16*)ws;
    float* W2t = (float*)(h + 8 * WSZ);
    const int k = blockIdx.x;
    const int j = threadIdx.x;
    {
        float a = mW1[k * H + j];
        _Float16 hi = (_Float16)a;
        _Float16 lo = (_Float16)(a - (float)hi);
        h[0 * WSZ + j * H + k] = hi;
        h[1 * WSZ + j * H + k] = lo;
        h[2 * WSZ + k * H + j] = hi;
        h[3 * WSZ + k * H + j] = lo;
    }
    {
        float a = vW1[k * H + j];
        _Float16 hi = (_Float16)a;
        _Float16 lo = (_Float16)(a - (float)hi);
        h[4 * WSZ + j * H + k] = hi;
        h[5 * WSZ + j * H + k] = lo;
        h[6 * WSZ + k * H + j] = hi;
        h[7 * WSZ + k * H + j] = lo;
    }
    if (k < NTRI) W2t[k * H + j] = mW2[j * NTRI + k];
}

__global__ __launch_bounds__(256, 2) void lnn_kernel(
    const float* __restrict__ x,
    const float* __restrict__ mW0, const float* __restrict__ mb0,
    const float* __restrict__ mb1,
    const float* __restrict__ mW2, const float* __restrict__ mb2,
    const float* __restrict__ vW0, const float* __restrict__ vb0,
    const float* __restrict__ vb1,
    const float* __restrict__ vW2,
    const void* __restrict__ ws,
    float* __restrict__ out, int n)
{
    const _Float16* wsh = (const _Float16*)ws;
    const _Float16* W1t_hi = wsh + 0 * WSZ;
    const _Float16* W1t_lo = wsh + 1 * WSZ;
    const _Float16* W1m_hi = wsh + 2 * WSZ;
    const _Float16* W1m_lo = wsh + 3 * WSZ;
    const _Float16* V1t_hi = wsh + 4 * WSZ;
    const _Float16* V1t_lo = wsh + 5 * WSZ;
    const _Float16* V1m_hi = wsh + 6 * WSZ;
    const _Float16* V1m_lo = wsh + 7 * WSZ;
    const float*    W2t    = (const float*)(wsh + 8 * WSZ);

    __shared__ float s_qd[EPB][10];
    __shared__ float s_h1[EPB][PADH];
    __shared__ float s_h2[EPB][PADH];
    __shared__ float s_sd[32][PADH];
    __shared__ float s_ent[EPB][NTRI];
    __shared__ float s_entbar[EPB][4][NTRI];
    __shared__ float s_Jp[4][EPB][4][6];
    __shared__ float s_dVp[4][EPB][6];
    __shared__ float s_L[EPB][16];

    const int tid = threadIdx.x;
    const int e0 = blockIdx.x * EPB;
    const int lane = tid & 63;
    const int wid = tid >> 6;
    const int fr = lane & 15;
    const int fg = lane >> 4;
    const int kb = fg * 8;

    // ---- load q, dq ----
    if (tid < EPB * 10) {
        int e = tid / 10, c = tid % 10;
        int ge = e0 + e;
        s_qd[e][c] = (ge < n) ? x[ge * 10 + c] : 0.f;
    }
    __syncthreads();

    // ================= V chain =================
    phase_layer0(s_qd, vW0, vb0, s_h1, tid);
    __syncthreads();

    phase_fwd(s_h1, V1t_hi, V1t_lo, vb1, vW2, s_h2, wid, fr, fg, kb);
    __syncthreads();

    phase_bwd_dV(s_h2, V1m_hi, V1m_lo, vW0, s_h1, s_dVp, wid, fr, fg, kb);
    __syncthreads();

    // ================= mass chain =================
    phase_layer0(s_qd, mW0, mb0, s_h1, tid);
    __syncthreads();

    phase_fwd(s_h1, W1t_hi, W1t_lo, mb1, nullptr, s_h2, wid, fr, fg, kb);
    __syncthreads();

    // ---- ent = h2 @ W2 + b2 ----
    if (tid < EPB * NTRI) {
        int e = tid / NTRI, m = tid % NTRI;
        float acc = mb2[m];
        const float* wrow = &W2t[m * H];
        for (int j = 0; j < H; j += 4) {
            const float2 h0 = *(const float2*)&s_h2[e][j];
            const float2 h1 = *(const float2*)&s_h2[e][j + 2];
            const float4 wv = *(const float4*)&wrow[j];
            acc += h0.x * wv.x + h0.y * wv.y + h1.x * wv.z + h1.y * wv.w;
        }
        s_ent[e][m] = acc;
    }
    __syncthreads();

    // ---- per-element: L (to LDS), a = L^T dq, ent_bar seeds ----
    if (tid < EPB) {
        const int e = tid;
        const int ti[10] = {0,1,1,2,2,2,3,3,3,3};
        const int tj[10] = {0,0,1,0,1,2,0,1,2,3};
        float L[4][4];
        #pragma unroll
        for (int r = 0; r < 4; r++)
            #pragma unroll
            for (int c = 0; c < 4; c++) L[r][c] = 0.f;
        float sig[10];
        #pragma unroll
        for (int m = 0; m < 10; m++) {
            float v = s_ent[e][m];
            if (ti[m] == tj[m]) {
                sig[m] = 1.f / (1.f + expf(-v));
                L[ti[m]][tj[m]] = softplusf(v);
            } else {
                sig[m] = 1.f;
                L[ti[m]][tj[m]] = v;
            }
        }
        #pragma unroll
        for (int r = 0; r < 4; r++)
            #pragma unroll
            for (int c = 0; c < 4; c++) s_L[e][r * 4 + c] = L[r][c];
        float dq[4];
        #pragma unroll
        for (int r = 0; r < 4; r++) dq[r] = s_qd[e][6 + r];
        float a[4];
        #pragma unroll
        for (int c = 0; c < 4; c++) {
            float s = 0.f;
            #pragma unroll
            for (int r = 0; r < 4; r++) s += L[r][c] * dq[r];
            a[c] = s;
        }
        #pragma unroll
        for (int s = 0; s < 4; s++) {
            #pragma unroll
            for (int m = 0; m < 10; m++) {
                float v = ((ti[m] == s) ? a[tj[m]] : 0.f) + dq[ti[m]] * L[s][tj[m]];
                s_entbar[e][s][m] = v * sig[m];
            }
        }
    }
    __syncthreads();

    // ---- Eh1 in 2 stages of 8 elements ----
    for (int hstage = 0; hstage < 2; hstage++) {
        {
            const int j = tid;
            float w2row[NTRI];
            #pragma unroll
            for (int m = 0; m < NTRI; m++) w2row[m] = mW2[j * NTRI + m];
            #pragma unroll 2
            for (int el = 0; el < 8; el++) {
                const int e = hstage * 8 + el;
                const float h = s_h2[e][j];
                const float t2 = 1.f - h * h;
                #pragma unroll
                for (int s = 0; s < 4; s++) {
                    float acc = 0.f;
                    #pragma unroll
                    for (int m = 0; m < NTRI; m++) acc += w2row[m] * s_entbar[e][s][m];
                    s_sd[el * 4 + s][j] = acc * t2;
                }
            }
        }
        __syncthreads();

        phase_eh1(s_sd, W1m_hi, W1m_lo, mW0, s_h1, s_Jp, hstage, wid, fr, fg, kb);
        __syncthreads();
    }

    // ---- finalize per element ----
    if (tid < EPB && (e0 + tid) < n) {
        const int e = tid;
        float q[6], dq[4];
        #pragma unroll
        for (int i = 0; i < 6; i++) q[i] = s_qd[e][i];
        #pragma unroll
        for (int r = 0; r < 4; r++) dq[r] = s_qd[e][6 + r];
        const float x1a = q[2], x1b = q[3], x2a = q[4], x2b = q[5];
        float J[4][6];
        #pragma unroll
        for (int r = 0; r < 4; r++)
            #pragma unroll
            for (int i = 0; i < 6; i++)
                J[r][i] = s_Jp[0][e][r][i] + s_Jp[1][e][r][i] + s_Jp[2][e][r][i] + s_Jp[3][e][r][i];
        float dV[6];
        #pragma unroll
        for (int i = 0; i < 6; i++)
            dV[i] = s_dVp[0][e][i] + s_dVp[1][e][i] + s_dVp[2][e][i] + s_dVp[3][e][i];

        float G[4][4];
        #pragma unroll
        for (int r = 0; r < 4; r++) {
            G[r][0] = J[r][0];
            G[r][1] = J[r][1];
            G[r][2] = -x2a * J[r][2] + x1a * J[r][4];
            G[r][3] = -x2b * J[r][3] + x1b * J[r][5];
        }
        float gL[6];
        #pragma unroll
        for (int i = 0; i < 6; i++) {
            float s = 0.f;
            #pragma unroll
            for (int r = 0; r < 4; r++) s += dq[r] * J[r][i];
            gL[i] = 0.5f * s - dV[i];
        }
        float dLdq[4];
        dLdq[0] = gL[0];
        dLdq[1] = gL[1];
        dLdq[2] = -x2a * gL[2] + x1a * gL[4];
        dLdq[3] = -x2b * gL[3] + x1b * gL[5];
        float b[4];
        #pragma unroll
        for (int r = 0; r < 4; r++) {
            float s = 0.f;
            #pragma unroll
            for (int c = 0; c < 4; c++) s += G[r][c] * dq[c];
            b[r] = dLdq[r] - s;
        }
        float M[4][4];
        #pragma unroll
        for (int r = 0; r < 4; r++)
            #pragma unroll
            for (int c = 0; c <= r; c++) {
                float s = 0.f;
                #pragma unroll
                for (int k = 0; k < 4; k++) s += s_L[e][r * 4 + k] * s_L[e][c * 4 + k];
                M[r][c] = s;
            }
        #pragma unroll
        for (int r = 0; r < 4; r++) M[r][r] += EPS;
        float C00 = sqrtf(M[0][0]);
        float C10 = M[1][0] / C00, C20 = M[2][0] / C00, C30 = M[3][0] / C00;
        float C11 = sqrtf(M[1][1] - C10 * C10);
        float C21 = (M[2][1] - C20 * C10) / C11;
        float C31 = (M[3][1] - C30 * C10) / C11;
        float C22 = sqrtf(M[2][2] - C20 * C20 - C21 * C21);
        float C32 = (M[3][2] - C30 * C20 - C31 * C21) / C22;
        float C33 = sqrtf(M[3][3] - C30 * C30 - C31 * C31 - C32 * C32);
        float y0 = b[0] / C00;
        float y1 = (b[1] - C10 * y0) / C11;
        float y2 = (b[2] - C20 * y0 - C21 * y1) / C22;
        float y3 = (b[3] - C30 * y0 - C31 * y1 - C32 * y2) / C33;
        float d3 = y3 / C33;
        float d2 = (y2 - C32 * d3) / C22;
        float d1 = (y1 - C21 * d2 - C31 * d3) / C11;
        float d0 = (y0 - C10 * d1 - C20 * d2 - C30 * d3) / C00;

        float* o = &out[(e0 + e) * 10];
        o[0] = dq[0];
        o[1] = dq[1];
        o[2] = -x2a * dq[2];
        o[3] = -x2b * dq[3];
        o[4] = x1a * dq[2];
        o[5] = x1b * dq[3];
        o[6] = d0; o[7] = d1; o[8] = d2; o[9] = d3;
    }
}

extern "C" void kernel_launch(void* const* d_in, const int* in_sizes, int n_in,
                              void* d_out, int out_size, void* d_ws, size_t ws_size,
                              hipStream_t stream) {
    const float* x   = (const float*)d_in[0];
    const float* mW0 = (const float*)d_in[1];
    const float* mb0 = (const float*)d_in[2];
    const float* mW1 = (const float*)d_in[3];
    const float* mb1 = (const float*)d_in[4];
    const float* mW2 = (const float*)d_in[5];
    const float* mb2 = (const float*)d_in[6];
    const float* vW0 = (const float*)d_in[7];
    const float* vb0 = (const float*)d_in[8];
    const float* vW1 = (const float*)d_in[9];
    const float* vb1 = (const float*)d_in[10];
    const float* vW2 = (const float*)d_in[11];
    float* out = (float*)d_out;
    const int n = in_sizes[0] / 10;

    prep_kernel<<<H, H, 0, stream>>>(mW1, vW1, mW2, d_ws);

    const int blocks = (n + EPB - 1) / EPB;
    lnn_kernel<<<blocks, 256, 0, stream>>>(x, mW0, mb0, mb1, mW2, mb2,
                                           vW0, vb0, vb1, vW2,
                                           d_ws, out, n);
}

// Round 17
// 789.186 us; speedup vs baseline: 1.2371x; 1.0023x over previous
//
#include <hip/hip_runtime.h>
#include <math.h>

#define EPS 1e-3f
#define H 256
#define QDIM 6
#define NTRI 10
#define EPB 16
#define PADH 260   // fp32 row pad

typedef _Float16 half8 __attribute__((ext_vector_type(8)));
typedef float floatx4 __attribute__((ext_vector_type(4)));

#define WSZ (H * H)

__device__ __forceinline__ float softplusf(float x) {
    if (x > 20.f) return x;
    return log1pf(expf(x));
}

__device__ __forceinline__ void split8(const float* __restrict__ p, half8& hi, half8& lo) {
    #pragma unroll
    for (int i = 0; i < 8; i++) {
        float a = p[i];
        _Float16 h = (_Float16)a;
        hi[i] = h;
        lo[i] = (_Float16)(a - (float)h);
    }
}

#define MFMA(A, B, C) __builtin_amdgcn_mfma_f32_16x16x32_f16((A), (B), (C), 0, 0, 0)

// 16-row A x 64-col B, kc-level 4-tile double-buffered prefetch
// (load->use distance = one full kc step = 12 MFMAs + splits)
__device__ __forceinline__ void gemm16(
    const float (*__restrict__ Arows)[PADH],
    const _Float16* __restrict__ Bhi, const _Float16* __restrict__ Blo,
    int wid, int fr, int kb, floatx4 (&acc)[4])
{
    half8 bhA[4], blA[4], bhB[4], blB[4];
    auto PREF = [&](half8 (&bh)[4], half8 (&bl)[4], int kc) {
        #pragma unroll
        for (int t = 0; t < 4; t++) {
            const int off = ((wid * 4 + t) * 16 + fr) * H + kc * 32 + kb;
            bh[t] = *(const half8*)&Bhi[off];
            bl[t] = *(const half8*)&Blo[off];
        }
    };
    auto STEP = [&](half8 (&bh)[4], half8 (&bl)[4], int kc) {
        half8 ah, al;
        split8(&Arows[fr][kc * 32 + kb], ah, al);
        #pragma unroll
        for (int t = 0; t < 4; t++) {
            acc[t] = MFMA(ah, bh[t], acc[t]);
            acc[t] = MFMA(ah, bl[t], acc[t]);
            acc[t] = MFMA(al, bh[t], acc[t]);
        }
    };
    PREF(bhA, blA, 0);
    PREF(bhB, blB, 1); STEP(bhA, blA, 0);
    PREF(bhA, blA, 2); STEP(bhB, blB, 1);
    PREF(bhB, blB, 3); STEP(bhA, blA, 2);
    PREF(bhA, blA, 4); STEP(bhB, blB, 3);
    PREF(bhB, blB, 5); STEP(bhA, blA, 4);
    PREF(bhA, blA, 6); STEP(bhB, blB, 5);
    PREF(bhB, blB, 7); STEP(bhA, blA, 6);
    STEP(bhB, blB, 7);
}

// 32-row A variant, acc[4][2], same prefetch scheme
__device__ __forceinline__ void gemm32(
    const float (*__restrict__ Arows)[PADH],
    const _Float16* __restrict__ Bhi, const _Float16* __restrict__ Blo,
    int wid, int fr, int kb, floatx4 (&acc)[4][2])
{
    half8 bhA[4], blA[4], bhB[4], blB[4];
    auto PREF = [&](half8 (&bh)[4], half8 (&bl)[4], int kc) {
        #pragma unroll
        for (int t = 0; t < 4; t++) {
            const int off = ((wid * 4 + t) * 16 + fr) * H + kc * 32 + kb;
            bh[t] = *(const half8*)&Bhi[off];
            bl[t] = *(const half8*)&Blo[off];
        }
    };
    auto STEP = [&](half8 (&bh)[4], half8 (&bl)[4], int kc) {
        half8 ah[2], al[2];
        #pragma unroll
        for (int mt = 0; mt < 2; mt++)
            split8(&Arows[mt * 16 + fr][kc * 32 + kb], ah[mt], al[mt]);
        #pragma unroll
        for (int t = 0; t < 4; t++) {
            #pragma unroll
            for (int mt = 0; mt < 2; mt++) {
                acc[t][mt] = MFMA(ah[mt], bh[t], acc[t][mt]);
                acc[t][mt] = MFMA(ah[mt], bl[t], acc[t][mt]);
                acc[t][mt] = MFMA(al[mt], bh[t], acc[t][mt]);
            }
        }
    };
    PREF(bhA, blA, 0);
    PREF(bhB, blB, 1); STEP(bhA, blA, 0);
    PREF(bhA, blA, 2); STEP(bhB, blB, 1);
    PREF(bhB, blB, 3); STEP(bhA, blA, 2);
    PREF(bhA, blA, 4); STEP(bhB, blB, 3);
    PREF(bhB, blB, 5); STEP(bhA, blA, 4);
    PREF(bhA, blA, 6); STEP(bhB, blB, 5);
    PREF(bhB, blB, 7); STEP(bhA, blA, 6);
    STEP(bhB, blB, 7);
}

// ---------- noinline phase functions: isolate register allocation ----------

__device__ __noinline__ void phase_layer0(
    const float (*__restrict__ s_qd)[10],
    const float* __restrict__ W0, const float* __restrict__ b0,
    float (*__restrict__ Aout)[PADH], int tid)
{
    const int j = tid;
    float w[QDIM];
    #pragma unroll
    for (int i = 0; i < QDIM; i++) w[i] = W0[i * H + j];
    const float b = b0[j];
    #pragma unroll 4
    for (int e = 0; e < EPB; e++) {
        float z = b;
        #pragma unroll
        for (int i = 0; i < QDIM; i++) z += s_qd[e][i] * w[i];
        Aout[e][j] = tanhf(z);
    }
}

__device__ __noinline__ void phase_fwd(
    const float (*__restrict__ Ain)[PADH],
    const _Float16* __restrict__ Bhi, const _Float16* __restrict__ Blo,
    const float* __restrict__ bias, const float* __restrict__ w2opt,
    float (*__restrict__ Aout)[PADH], int wid, int fr, int fg, int kb)
{
    floatx4 acc[4];
    #pragma unroll
    for (int t = 0; t < 4; t++) acc[t] = (floatx4)(0.f);
    gemm16(Ain, Bhi, Blo, wid, fr, kb, acc);
    #pragma unroll
    for (int t = 0; t < 4; t++) {
        const int j = (wid * 4 + t) * 16 + fr;
        const float b = bias[j];
        if (w2opt) {
            const float w2 = w2opt[j];
            #pragma unroll
            for (int rr = 0; rr < 4; rr++) {
                const float g2 = tanhf(acc[t][rr] + b);
                Aout[fg * 4 + rr][j] = (1.f - g2 * g2) * w2;
            }
        } else {
            #pragma unroll
            for (int rr = 0; rr < 4; rr++)
                Aout[fg * 4 + rr][j] = tanhf(acc[t][rr] + b);
        }
    }
}

__device__ __noinline__ void phase_bwd_dV(
    const float (*__restrict__ Ain)[PADH],
    const _Float16* __restrict__ Bhi, const _Float16* __restrict__ Blo,
    const float* __restrict__ vW0, const float (*__restrict__ g1)[PADH],
    float (*__restrict__ dVp)[EPB][6], int wid, int fr, int fg, int kb)
{
    floatx4 acc[4];
    #pragma unroll
    for (int t = 0; t < 4; t++) acc[t] = (floatx4)(0.f);
    gemm16(Ain, Bhi, Blo, wid, fr, kb, acc);

    float part[4][6];
    #pragma unroll
    for (int rr = 0; rr < 4; rr++)
        #pragma unroll
        for (int i = 0; i < 6; i++) part[rr][i] = 0.f;
    #pragma unroll
    for (int t = 0; t < 4; t++) {
        const int outk = (wid * 4 + t) * 16 + fr;
        float w0[6];
        #pragma unroll
        for (int i = 0; i < 6; i++) w0[i] = vW0[i * H + outk];
        #pragma unroll
        for (int rr = 0; rr < 4; rr++) {
            const float g = g1[fg * 4 + rr][outk];
            const float t1 = 1.f - g * g;
            const float v = acc[t][rr] * t1;
            #pragma unroll
            for (int i = 0; i < 6; i++) part[rr][i] = fmaf(v, w0[i], part[rr][i]);
        }
    }
    #pragma unroll
    for (int m = 1; m < 16; m <<= 1)
        #pragma unroll
        for (int rr = 0; rr < 4; rr++)
            #pragma unroll
            for (int i = 0; i < 6; i++)
                part[rr][i] += __shfl_xor(part[rr][i], m);
    if (fr == 0) {
        #pragma unroll
        for (int rr = 0; rr < 4; rr++)
            #pragma unroll
            for (int i = 0; i < 6; i++)
                dVp[wid][fg * 4 + rr][i] = part[rr][i];
    }
}

__device__ __noinline__ void phase_eh1(
    const float (*__restrict__ sd)[PADH],
    const _Float16* __restrict__ Bhi, const _Float16* __restrict__ Blo,
    const float* __restrict__ mW0, const float (*__restrict__ h1)[PADH],
    float (*__restrict__ Jp)[EPB][4][6], int hstage, int wid, int fr, int fg, int kb)
{
    floatx4 acc[4][2];
    #pragma unroll
    for (int t = 0; t < 4; t++)
        #pragma unroll
        for (int mt = 0; mt < 2; mt++) acc[t][mt] = (floatx4)(0.f);
    gemm32(sd, Bhi, Blo, wid, fr, kb, acc);

    #pragma unroll
    for (int mt = 0; mt < 2; mt++) {
        const int e = hstage * 8 + mt * 4 + fg;
        float part[4][6];
        #pragma unroll
        for (int rr = 0; rr < 4; rr++)
            #pragma unroll
            for (int i = 0; i < 6; i++) part[rr][i] = 0.f;
        #pragma unroll
        for (int t = 0; t < 4; t++) {
            const int outk = (wid * 4 + t) * 16 + fr;
            float w0[6];
            #pragma unroll
            for (int i = 0; i < 6; i++) w0[i] = mW0[i * H + outk];
            const float h = h1[e][outk];
            const float t1 = 1.f - h * h;
            #pragma unroll
            for (int rr = 0; rr < 4; rr++) {
                const float v = acc[t][mt][rr] * t1;
                #pragma unroll
                for (int i = 0; i < 6; i++) part[rr][i] = fmaf(v, w0[i], part[rr][i]);
            }
        }
        #pragma unroll
        for (int m = 1; m < 16; m <<= 1)
            #pragma unroll
            for (int rr = 0; rr < 4; rr++)
                #pragma unroll
                for (int i = 0; i < 6; i++)
                    part[rr][i] += __shfl_xor(part[rr][i], m);
        if (fr == 0) {
            #pragma unroll
            for (int rr = 0; rr < 4; rr++)
                #pragma unroll
                for (int i = 0; i < 6; i++)
                    Jp[wid][e][rr][i] = part[rr][i];
        }
    }
}

// ---- prep: pre-split weights to fp16 hi/lo in both layouts; transpose mW2 ----
__global__ __launch_bounds__(256) void prep_kernel(
    const float* __restrict__ mW1, const float* __restrict__ vW1,
    const float* __restrict__ mW2, void* __restrict__ ws)
{
    _Float16* h = (_Float16*)ws;
    float* W2t = (float*)(h + 8 * WSZ);
    const int k = blockIdx.x;
    const int j = threadIdx.x;
    {
        float a = mW1[k * H + j];
        _Float16 hi = (_Float16)a;
        _Float16 lo = (_Float16)(a - (float)hi);
        h[0 * WSZ + j * H + k] = hi;
        h[1 * WSZ + j * H + k] = lo;
        h[2 * WSZ + k * H + j] = hi;
        h[3 * WSZ + k * H + j] = lo;
    }
    {
        float a = vW1[k * H + j];
        _Float16 hi = (_Float16)a;
        _Float16 lo = (_Float16)(a - (float)hi);
        h[4 * WSZ + j * H + k] = hi;
        h[5 * WSZ + j * H + k] = lo;
        h[6 * WSZ + k * H + j] = hi;
        h[7 * WSZ + k * H + j] = lo;
    }
    if (k < NTRI) W2t[k * H + j] = mW2[j * NTRI + k];
}

__global__ __launch_bounds__(256) void lnn_kernel(
    const float* __restrict__ x,
    const float* __restrict__ mW0, const float* __restrict__ mb0,
    const float* __restrict__ mb1,
    const float* __restrict__ mW2, const float* __restrict__ mb2,
    const float* __restrict__ vW0, const float* __restrict__ vb0,
    const float* __restrict__ vb1,
    const float* __restrict__ vW2,
    const void* __restrict__ ws,
    float* __restrict__ out, int n)
{
    const _Float16* wsh = (const _Float16*)ws;
    const _Float16* W1t_hi = wsh + 0 * WSZ;
    const _Float16* W1t_lo = wsh + 1 * WSZ;
    const _Float16* W1m_hi = wsh + 2 * WSZ;
    const _Float16* W1m_lo = wsh + 3 * WSZ;
    const _Float16* V1t_hi = wsh + 4 * WSZ;
    const _Float16* V1t_lo = wsh + 5 * WSZ;
    const _Float16* V1m_hi = wsh + 6 * WSZ;
    const _Float16* V1m_lo = wsh + 7 * WSZ;
    const float*    W2t    = (const float*)(wsh + 8 * WSZ);

    __shared__ float s_qd[EPB][10];
    __shared__ float s_h1[EPB][PADH];
    __shared__ float s_h2[EPB][PADH];
    __shared__ float s_sd[32][PADH];
    __shared__ float s_ent[EPB][NTRI];
    __shared__ float s_entbar[EPB][4][NTRI];
    __shared__ float s_Jp[4][EPB][4][6];
    __shared__ float s_dVp[4][EPB][6];
    __shared__ float s_L[EPB][16];

    const int tid = threadIdx.x;
    const int e0 = blockIdx.x * EPB;
    const int lane = tid & 63;
    const int wid = tid >> 6;
    const int fr = lane & 15;
    const int fg = lane >> 4;
    const int kb = fg * 8;

    // ---- load q, dq ----
    if (tid < EPB * 10) {
        int e = tid / 10, c = tid % 10;
        int ge = e0 + e;
        s_qd[e][c] = (ge < n) ? x[ge * 10 + c] : 0.f;
    }
    __syncthreads();

    // ================= V chain =================
    phase_layer0(s_qd, vW0, vb0, s_h1, tid);
    __syncthreads();

    phase_fwd(s_h1, V1t_hi, V1t_lo, vb1, vW2, s_h2, wid, fr, fg, kb);
    __syncthreads();

    phase_bwd_dV(s_h2, V1m_hi, V1m_lo, vW0, s_h1, s_dVp, wid, fr, fg, kb);
    __syncthreads();

    // ================= mass chain =================
    phase_layer0(s_qd, mW0, mb0, s_h1, tid);
    __syncthreads();

    phase_fwd(s_h1, W1t_hi, W1t_lo, mb1, nullptr, s_h2, wid, fr, fg, kb);
    __syncthreads();

    // ---- ent = h2 @ W2 + b2 ----
    if (tid < EPB * NTRI) {
        int e = tid / NTRI, m = tid % NTRI;
        float acc = mb2[m];
        const float* wrow = &W2t[m * H];
        for (int j = 0; j < H; j += 4) {
            const float2 h0 = *(const float2*)&s_h2[e][j];
            const float2 h1 = *(const float2*)&s_h2[e][j + 2];
            const float4 wv = *(const float4*)&wrow[j];
            acc += h0.x * wv.x + h0.y * wv.y + h1.x * wv.z + h1.y * wv.w;
        }
        s_ent[e][m] = acc;
    }
    __syncthreads();

    // ---- per-element: L (to LDS), a = L^T dq, ent_bar seeds ----
    if (tid < EPB) {
        const int e = tid;
        const int ti[10] = {0,1,1,2,2,2,3,3,3,3};
        const int tj[10] = {0,0,1,0,1,2,0,1,2,3};
        float L[4][4];
        #pragma unroll
        for (int r = 0; r < 4; r++)
            #pragma unroll
            for (int c = 0; c < 4; c++) L[r][c] = 0.f;
        float sig[10];
        #pragma unroll
        for (int m = 0; m < 10; m++) {
            float v = s_ent[e][m];
            if (ti[m] == tj[m]) {
                sig[m] = 1.f / (1.f + expf(-v));
                L[ti[m]][tj[m]] = softplusf(v);
            } else {
                sig[m] = 1.f;
                L[ti[m]][tj[m]] = v;
            }
        }
        #pragma unroll
        for (int r = 0; r < 4; r++)
            #pragma unroll
            for (int c = 0; c < 4; c++) s_L[e][r * 4 + c] = L[r][c];
        float dq[4];
        #pragma unroll
        for (int r = 0; r < 4; r++) dq[r] = s_qd[e][6 + r];
        float a[4];
        #pragma unroll
        for (int c = 0; c < 4; c++) {
            float s = 0.f;
            #pragma unroll
            for (int r = 0; r < 4; r++) s += L[r][c] * dq[r];
            a[c] = s;
        }
        #pragma unroll
        for (int s = 0; s < 4; s++) {
            #pragma unroll
            for (int m = 0; m < 10; m++) {
                float v = ((ti[m] == s) ? a[tj[m]] : 0.f) + dq[ti[m]] * L[s][tj[m]];
                s_entbar[e][s][m] = v * sig[m];
            }
        }
    }
    __syncthreads();

    // ---- Eh1 in 2 stages of 8 elements ----
    for (int hstage = 0; hstage < 2; hstage++) {
        {
            const int j = tid;
            float w2row[NTRI];
            #pragma unroll
            for (int m = 0; m < NTRI; m++) w2row[m] = mW2[j * NTRI + m];
            #pragma unroll 2
            for (int el = 0; el < 8; el++) {
                const int e = hstage * 8 + el;
                const float h = s_h2[e][j];
                const float t2 = 1.f - h * h;
                #pragma unroll
                for (int s = 0; s < 4; s++) {
                    float acc = 0.f;
                    #pragma unroll
                    for (int m = 0; m < NTRI; m++) acc += w2row[m] * s_entbar[e][s][m];
                    s_sd[el * 4 + s][j] = acc * t2;
                }
            }
        }
        __syncthreads();

        phase_eh1(s_sd, W1m_hi, W1m_lo, mW0, s_h1, s_Jp, hstage, wid, fr, fg, kb);
        __syncthreads();
    }

    // ---- finalize per element ----
    if (tid < EPB && (e0 + tid) < n) {
        const int e = tid;
        float q[6], dq[4];
        #pragma unroll
        for (int i = 0; i < 6; i++) q[i] = s_qd[e][i];
        #pragma unroll
        for (int r = 0; r < 4; r++) dq[r] = s_qd[e][6 + r];
        const float x1a = q[2], x1b = q[3], x2a = q[4], x2b = q[5];
        float J[4][6];
        #pragma unroll
        for (int r = 0; r < 4; r++)
            #pragma unroll
            for (int i = 0; i < 6; i++)
                J[r][i] = s_Jp[0][e][r][i] + s_Jp[1][e][r][i] + s_Jp[2][e][r][i] + s_Jp[3][e][r][i];
        float dV[6];
        #pragma unroll
        for (int i = 0; i < 6; i++)
            dV[i] = s_dVp[0][e][i] + s_dVp[1][e][i] + s_dVp[2][e][i] + s_dVp[3][e][i];

        float G[4][4];
        #pragma unroll
        for (int r = 0; r < 4; r++) {
            G[r][0] = J[r][0];
            G[r][1] = J[r][1];
            G[r][2] = -x2a * J[r][2] + x1a * J[r][4];
            G[r][3] = -x2b * J[r][3] + x1b * J[r][5];
        }
        float gL[6];
        #pragma unroll
        for (int i = 0; i < 6; i++) {
            float s = 0.f;
            #pragma unroll
            for (int r = 0; r < 4; r++) s += dq[r] * J[r][i];
            gL[i] = 0.5f * s - dV[i];
        }
        float dLdq[4];
        dLdq[0] = gL[0];
        dLdq[1] = gL[1];
        dLdq[2] = -x2a * gL[2] + x1a * gL[4];
        dLdq[3] = -x2b * gL[3] + x1b * gL[5];
        float b[4];
        #pragma unroll
        for (int r = 0; r < 4; r++) {
            float s = 0.f;
            #pragma unroll
            for (int c = 0; c < 4; c++) s += G[r][c] * dq[c];
            b[r] = dLdq[r] - s;
        }
        float M[4][4];
        #pragma unroll
        for (int r = 0; r < 4; r++)
            #pragma unroll
            for (int c = 0; c <= r; c++) {
                float s = 0.f;
                #pragma unroll
                for (int k = 0; k < 4; k++) s += s_L[e][r * 4 + k] * s_L[e][c * 4 + k];
                M[r][c] = s;
            }
        #pragma unroll
        for (int r = 0; r < 4; r++) M[r][r] += EPS;
        float C00 = sqrtf(M[0][0]);
        float C10 = M[1][0] / C00, C20 = M[2][0] / C00, C30 = M[3][0] / C00;
        float C11 = sqrtf(M[1][1] - C10 * C10);
        float C21 = (M[2][1] - C20 * C10) / C11;
        float C31 = (M[3][1] - C30 * C10) / C11;
        float C22 = sqrtf(M[2][2] - C20 * C20 - C21 * C21);
        float C32 = (M[3][2] - C30 * C20 - C31 * C21) / C22;
        float C33 = sqrtf(M[3][3] - C30 * C30 - C31 * C31 - C32 * C32);
        float y0 = b[0] / C00;
        float y1 = (b[1] - C10 * y0) / C11;
        float y2 = (b[2] - C20 * y0 - C21 * y1) / C22;
        float y3 = (b[3] - C30 * y0 - C31 * y1 - C32 * y2) / C33;
        float d3 = y3 / C33;
        float d2 = (y2 - C32 * d3) / C22;
        float d1 = (y1 - C21 * d2 - C31 * d3) / C11;
        float d0 = (y0 - C10 * d1 - C20 * d2 - C30 * d3) / C00;

        float* o = &out[(e0 + e) * 10];
        o[0] = dq[0];
        o[1] = dq[1];
        o[2] = -x2a * dq[2];
        o[3] = -x2b * dq[3];
        o[4] = x1a * dq[2];
        o[5] = x1b * dq[3];
        o[6] = d0; o[7] = d1; o[8] = d2; o[9] = d3;
    }
}

extern "C" void kernel_launch(void* const* d_in, const int* in_sizes, int n_in,
                              void* d_out, int out_size, void* d_ws, size_t ws_size,
                              hipStream_t stream) {
    const float* x   = (const float*)d_in[0];
    const float* mW0 = (const float*)d_in[1];
    const float* mb0 = (const float*)d_in[2];
    const float* mW1 = (const float*)d_in[3];
    const float* mb1 = (const float*)d_in[4];
    const float* mW2 = (const float*)d_in[5];
    const float* mb2 = (const float*)d_in[6];
    const float* vW0 = (const float*)d_in[7];
    const float* vb0 = (const float*)d_in[8];
    const float* vW1 = (const float*)d_in[9];
    const float* vb1 = (const float*)d_in[10];
    const float* vW2 = (const float*)d_in[11];
    float* out = (float*)d_out;
    const int n = in_sizes[0] / 10;

    prep_kernel<<<H, H, 0, stream>>>(mW1, vW1, mW2, d_ws);

    const int blocks = (n + EPB - 1) / EPB;
    lnn_kernel<<<blocks, 256, 0, stream>>>(x, mW0, mb0, mb1, mW2, mb2,
                                           vW0, vb0, vb1, vW2,
                                           d_ws, out, n);
}

// Round 18
// 753.032 us; speedup vs baseline: 1.2965x; 1.0480x over previous
//
#include <hip/hip_runtime.h>
#include <math.h>

#define EPS 1e-3f
#define H 256
#define QDIM 6
#define NTRI 10
#define EPB 16
#define PADH 264   // fp16 row pad: 528B rows, 16B-aligned, bank-stride 4 (2-way free)

typedef _Float16 half8 __attribute__((ext_vector_type(8)));
typedef float floatx4 __attribute__((ext_vector_type(4)));

#define WSZ (H * H)

__device__ __forceinline__ float softplusf(float x) {
    if (x > 20.f) return x;
    return log1pf(expf(x));
}

#define MFMA(A, B, C) __builtin_amdgcn_mfma_f32_16x16x32_f16((A), (B), (C), 0, 0, 0)

// 16-row fp16 A (LDS) x 64-col B (pre-split fp16 hi/lo), deep 4-tile prefetch.
// A is fp16-rounded; B keeps full precision via hi+lo -> 2 MFMA per (kc,t).
__device__ __forceinline__ void gemm16(
    const _Float16 (*__restrict__ Arows)[PADH],
    const _Float16* __restrict__ Bhi, const _Float16* __restrict__ Blo,
    int wid, int fr, int kb, floatx4 (&acc)[4])
{
    half8 bhA[4], blA[4], bhB[4], blB[4];
    auto PREF = [&](half8 (&bh)[4], half8 (&bl)[4], int kc) {
        #pragma unroll
        for (int t = 0; t < 4; t++) {
            const int off = ((wid * 4 + t) * 16 + fr) * H + kc * 32 + kb;
            bh[t] = *(const half8*)&Bhi[off];
            bl[t] = *(const half8*)&Blo[off];
        }
    };
    auto STEP = [&](half8 (&bh)[4], half8 (&bl)[4], int kc) {
        const half8 ah = *(const half8*)&Arows[fr][kc * 32 + kb];
        #pragma unroll
        for (int t = 0; t < 4; t++) {
            acc[t] = MFMA(ah, bh[t], acc[t]);
            acc[t] = MFMA(ah, bl[t], acc[t]);
        }
    };
    PREF(bhA, blA, 0);
    PREF(bhB, blB, 1); STEP(bhA, blA, 0);
    PREF(bhA, blA, 2); STEP(bhB, blB, 1);
    PREF(bhB, blB, 3); STEP(bhA, blA, 2);
    PREF(bhA, blA, 4); STEP(bhB, blB, 3);
    PREF(bhB, blB, 5); STEP(bhA, blA, 4);
    PREF(bhA, blA, 6); STEP(bhB, blB, 5);
    PREF(bhB, blB, 7); STEP(bhA, blA, 6);
    STEP(bhB, blB, 7);
}

// 32-row A variant, acc[4][2]
__device__ __forceinline__ void gemm32(
    const _Float16 (*__restrict__ Arows)[PADH],
    const _Float16* __restrict__ Bhi, const _Float16* __restrict__ Blo,
    int wid, int fr, int kb, floatx4 (&acc)[4][2])
{
    half8 bhA[4], blA[4], bhB[4], blB[4];
    auto PREF = [&](half8 (&bh)[4], half8 (&bl)[4], int kc) {
        #pragma unroll
        for (int t = 0; t < 4; t++) {
            const int off = ((wid * 4 + t) * 16 + fr) * H + kc * 32 + kb;
            bh[t] = *(const half8*)&Bhi[off];
            bl[t] = *(const half8*)&Blo[off];
        }
    };
    auto STEP = [&](half8 (&bh)[4], half8 (&bl)[4], int kc) {
        half8 ah[2];
        #pragma unroll
        for (int mt = 0; mt < 2; mt++)
            ah[mt] = *(const half8*)&Arows[mt * 16 + fr][kc * 32 + kb];
        #pragma unroll
        for (int t = 0; t < 4; t++) {
            #pragma unroll
            for (int mt = 0; mt < 2; mt++) {
                acc[t][mt] = MFMA(ah[mt], bh[t], acc[t][mt]);
                acc[t][mt] = MFMA(ah[mt], bl[t], acc[t][mt]);
            }
        }
    };
    PREF(bhA, blA, 0);
    PREF(bhB, blB, 1); STEP(bhA, blA, 0);
    PREF(bhA, blA, 2); STEP(bhB, blB, 1);
    PREF(bhB, blB, 3); STEP(bhA, blA, 2);
    PREF(bhA, blA, 4); STEP(bhB, blB, 3);
    PREF(bhB, blB, 5); STEP(bhA, blA, 4);
    PREF(bhA, blA, 6); STEP(bhB, blB, 5);
    PREF(bhB, blB, 7); STEP(bhA, blA, 6);
    STEP(bhB, blB, 7);
}

// ---------- noinline phase functions: isolate register allocation ----------

__device__ __noinline__ void phase_layer0(
    const float (*__restrict__ s_qd)[10],
    const float* __restrict__ W0, const float* __restrict__ b0,
    _Float16 (*__restrict__ Aout)[PADH], int tid)
{
    const int j = tid;
    float w[QDIM];
    #pragma unroll
    for (int i = 0; i < QDIM; i++) w[i] = W0[i * H + j];
    const float b = b0[j];
    #pragma unroll 4
    for (int e = 0; e < EPB; e++) {
        float z = b;
        #pragma unroll
        for (int i = 0; i < QDIM; i++) z += s_qd[e][i] * w[i];
        Aout[e][j] = (_Float16)tanhf(z);
    }
}

__device__ __noinline__ void phase_fwd(
    const _Float16 (*__restrict__ Ain)[PADH],
    const _Float16* __restrict__ Bhi, const _Float16* __restrict__ Blo,
    const float* __restrict__ bias, const float* __restrict__ w2opt,
    _Float16 (*__restrict__ Aout)[PADH], int wid, int fr, int fg, int kb)
{
    floatx4 acc[4];
    #pragma unroll
    for (int t = 0; t < 4; t++) acc[t] = (floatx4)(0.f);
    gemm16(Ain, Bhi, Blo, wid, fr, kb, acc);
    #pragma unroll
    for (int t = 0; t < 4; t++) {
        const int j = (wid * 4 + t) * 16 + fr;
        const float b = bias[j];
        if (w2opt) {
            const float w2 = w2opt[j];
            #pragma unroll
            for (int rr = 0; rr < 4; rr++) {
                const float g2 = tanhf(acc[t][rr] + b);
                Aout[fg * 4 + rr][j] = (_Float16)((1.f - g2 * g2) * w2);
            }
        } else {
            #pragma unroll
            for (int rr = 0; rr < 4; rr++)
                Aout[fg * 4 + rr][j] = (_Float16)tanhf(acc[t][rr] + b);
        }
    }
}

__device__ __noinline__ void phase_bwd_dV(
    const _Float16 (*__restrict__ Ain)[PADH],
    const _Float16* __restrict__ Bhi, const _Float16* __restrict__ Blo,
    const float* __restrict__ vW0, const _Float16 (*__restrict__ g1)[PADH],
    float (*__restrict__ dVp)[EPB][6], int wid, int fr, int fg, int kb)
{
    floatx4 acc[4];
    #pragma unroll
    for (int t = 0; t < 4; t++) acc[t] = (floatx4)(0.f);
    gemm16(Ain, Bhi, Blo, wid, fr, kb, acc);

    float part[4][6];
    #pragma unroll
    for (int rr = 0; rr < 4; rr++)
        #pragma unroll
        for (int i = 0; i < 6; i++) part[rr][i] = 0.f;
    #pragma unroll
    for (int t = 0; t < 4; t++) {
        const int outk = (wid * 4 + t) * 16 + fr;
        float w0[6];
        #pragma unroll
        for (int i = 0; i < 6; i++) w0[i] = vW0[i * H + outk];
        #pragma unroll
        for (int rr = 0; rr < 4; rr++) {
            const float g = (float)g1[fg * 4 + rr][outk];
            const float t1 = 1.f - g * g;
            const float v = acc[t][rr] * t1;
            #pragma unroll
            for (int i = 0; i < 6; i++) part[rr][i] = fmaf(v, w0[i], part[rr][i]);
        }
    }
    #pragma unroll
    for (int m = 1; m < 16; m <<= 1)
        #pragma unroll
        for (int rr = 0; rr < 4; rr++)
            #pragma unroll
            for (int i = 0; i < 6; i++)
                part[rr][i] += __shfl_xor(part[rr][i], m);
    if (fr == 0) {
        #pragma unroll
        for (int rr = 0; rr < 4; rr++)
            #pragma unroll
            for (int i = 0; i < 6; i++)
                dVp[wid][fg * 4 + rr][i] = part[rr][i];
    }
}

__device__ __noinline__ void phase_eh1(
    const _Float16 (*__restrict__ sd)[PADH],
    const _Float16* __restrict__ Bhi, const _Float16* __restrict__ Blo,
    const float* __restrict__ mW0, const _Float16 (*__restrict__ h1)[PADH],
    float (*__restrict__ Jp)[EPB][4][6], int hstage, int wid, int fr, int fg, int kb)
{
    floatx4 acc[4][2];
    #pragma unroll
    for (int t = 0; t < 4; t++)
        #pragma unroll
        for (int mt = 0; mt < 2; mt++) acc[t][mt] = (floatx4)(0.f);
    gemm32(sd, Bhi, Blo, wid, fr, kb, acc);

    #pragma unroll
    for (int mt = 0; mt < 2; mt++) {
        const int e = hstage * 8 + mt * 4 + fg;
        float part[4][6];
        #pragma unroll
        for (int rr = 0; rr < 4; rr++)
            #pragma unroll
            for (int i = 0; i < 6; i++) part[rr][i] = 0.f;
        #pragma unroll
        for (int t = 0; t < 4; t++) {
            const int outk = (wid * 4 + t) * 16 + fr;
            float w0[6];
            #pragma unroll
            for (int i = 0; i < 6; i++) w0[i] = mW0[i * H + outk];
            const float h = (float)h1[e][outk];
            const float t1 = 1.f - h * h;
            #pragma unroll
            for (int rr = 0; rr < 4; rr++) {
                const float v = acc[t][mt][rr] * t1;
                #pragma unroll
                for (int i = 0; i < 6; i++) part[rr][i] = fmaf(v, w0[i], part[rr][i]);
            }
        }
        #pragma unroll
        for (int m = 1; m < 16; m <<= 1)
            #pragma unroll
            for (int rr = 0; rr < 4; rr++)
                #pragma unroll
                for (int i = 0; i < 6; i++)
                    part[rr][i] += __shfl_xor(part[rr][i], m);
        if (fr == 0) {
            #pragma unroll
            for (int rr = 0; rr < 4; rr++)
                #pragma unroll
                for (int i = 0; i < 6; i++)
                    Jp[wid][e][rr][i] = part[rr][i];
        }
    }
}

// ---- prep: pre-split weights to fp16 hi/lo in both layouts; transpose mW2 ----
__global__ __launch_bounds__(256) void prep_kernel(
    const float* __restrict__ mW1, const float* __restrict__ vW1,
    const float* __restrict__ mW2, void* __restrict__ ws)
{
    _Float16* h = (_Float16*)ws;
    float* W2t = (float*)(h + 8 * WSZ);
    const int k = blockIdx.x;
    const int j = threadIdx.x;
    {
        float a = mW1[k * H + j];
        _Float16 hi = (_Float16)a;
        _Float16 lo = (_Float16)(a - (float)hi);
        h[0 * WSZ + j * H + k] = hi;
        h[1 * WSZ + j * H + k] = lo;
        h[2 * WSZ + k * H + j] = hi;
        h[3 * WSZ + k * H + j] = lo;
    }
    {
        float a = vW1[k * H + j];
        _Float16 hi = (_Float16)a;
        _Float16 lo = (_Float16)(a - (float)hi);
        h[4 * WSZ + j * H + k] = hi;
        h[5 * WSZ + j * H + k] = lo;
        h[6 * WSZ + k * H + j] = hi;
        h[7 * WSZ + k * H + j] = lo;
    }
    if (k < NTRI) W2t[k * H + j] = mW2[j * NTRI + k];
}

__global__ __launch_bounds__(256) void lnn_kernel(
    const float* __restrict__ x,
    const float* __restrict__ mW0, const float* __restrict__ mb0,
    const float* __restrict__ mb1,
    const float* __restrict__ mW2, const float* __restrict__ mb2,
    const float* __restrict__ vW0, const float* __restrict__ vb0,
    const float* __restrict__ vb1,
    const float* __restrict__ vW2,
    const void* __restrict__ ws,
    float* __restrict__ out, int n)
{
    const _Float16* wsh = (const _Float16*)ws;
    const _Float16* W1t_hi = wsh + 0 * WSZ;
    const _Float16* W1t_lo = wsh + 1 * WSZ;
    const _Float16* W1m_hi = wsh + 2 * WSZ;
    const _Float16* W1m_lo = wsh + 3 * WSZ;
    const _Float16* V1t_hi = wsh + 4 * WSZ;
    const _Float16* V1t_lo = wsh + 5 * WSZ;
    const _Float16* V1m_hi = wsh + 6 * WSZ;
    const _Float16* V1m_lo = wsh + 7 * WSZ;
    const float*    W2t    = (const float*)(wsh + 8 * WSZ);

    __shared__ float s_qd[EPB][10];
    __shared__ _Float16 __align__(16) s_h1[EPB][PADH];   // g1/h1 (fp16)
    __shared__ _Float16 __align__(16) s_h2[EPB][PADH];   // gg2/h2 (fp16)
    __shared__ _Float16 __align__(16) s_sd[32][PADH];    // Eh1 seeds (fp16)
    __shared__ float s_ent[EPB][NTRI];
    __shared__ float s_entbar[EPB][4][NTRI];
    __shared__ float s_Jp[4][EPB][4][6];
    __shared__ float s_dVp[4][EPB][6];
    __shared__ float s_L[EPB][16];

    const int tid = threadIdx.x;
    const int e0 = blockIdx.x * EPB;
    const int lane = tid & 63;
    const int wid = tid >> 6;
    const int fr = lane & 15;
    const int fg = lane >> 4;
    const int kb = fg * 8;

    // ---- load q, dq ----
    if (tid < EPB * 10) {
        int e = tid / 10, c = tid % 10;
        int ge = e0 + e;
        s_qd[e][c] = (ge < n) ? x[ge * 10 + c] : 0.f;
    }
    __syncthreads();

    // ================= V chain =================
    phase_layer0(s_qd, vW0, vb0, s_h1, tid);
    __syncthreads();

    phase_fwd(s_h1, V1t_hi, V1t_lo, vb1, vW2, s_h2, wid, fr, fg, kb);
    __syncthreads();

    phase_bwd_dV(s_h2, V1m_hi, V1m_lo, vW0, s_h1, s_dVp, wid, fr, fg, kb);
    __syncthreads();

    // ================= mass chain =================
    phase_layer0(s_qd, mW0, mb0, s_h1, tid);
    __syncthreads();

    phase_fwd(s_h1, W1t_hi, W1t_lo, mb1, nullptr, s_h2, wid, fr, fg, kb);
    __syncthreads();

    // ---- ent = h2 @ W2 + b2 ----
    if (tid < EPB * NTRI) {
        int e = tid / NTRI, m = tid % NTRI;
        float acc = mb2[m];
        const float* wrow = &W2t[m * H];
        for (int j = 0; j < H; j += 8) {
            const half8 hv = *(const half8*)&s_h2[e][j];
            const float4 w0 = *(const float4*)&wrow[j];
            const float4 w1 = *(const float4*)&wrow[j + 4];
            acc += (float)hv[0] * w0.x + (float)hv[1] * w0.y
                 + (float)hv[2] * w0.z + (float)hv[3] * w0.w
                 + (float)hv[4] * w1.x + (float)hv[5] * w1.y
                 + (float)hv[6] * w1.z + (float)hv[7] * w1.w;
        }
        s_ent[e][m] = acc;
    }
    __syncthreads();

    // ---- per-element: L (to LDS), a = L^T dq, ent_bar seeds ----
    if (tid < EPB) {
        const int e = tid;
        const int ti[10] = {0,1,1,2,2,2,3,3,3,3};
        const int tj[10] = {0,0,1,0,1,2,0,1,2,3};
        float L[4][4];
        #pragma unroll
        for (int r = 0; r < 4; r++)
            #pragma unroll
            for (int c = 0; c < 4; c++) L[r][c] = 0.f;
        float sig[10];
        #pragma unroll
        for (int m = 0; m < 10; m++) {
            float v = s_ent[e][m];
            if (ti[m] == tj[m]) {
                sig[m] = 1.f / (1.f + expf(-v));
                L[ti[m]][tj[m]] = softplusf(v);
            } else {
                sig[m] = 1.f;
                L[ti[m]][tj[m]] = v;
            }
        }
        #pragma unroll
        for (int r = 0; r < 4; r++)
            #pragma unroll
            for (int c = 0; c < 4; c++) s_L[e][r * 4 + c] = L[r][c];
        float dq[4];
        #pragma unroll
        for (int r = 0; r < 4; r++) dq[r] = s_qd[e][6 + r];
        float a[4];
        #pragma unroll
        for (int c = 0; c < 4; c++) {
            float s = 0.f;
            #pragma unroll
            for (int r = 0; r < 4; r++) s += L[r][c] * dq[r];
            a[c] = s;
        }
        #pragma unroll
        for (int s = 0; s < 4; s++) {
            #pragma unroll
            for (int m = 0; m < 10; m++) {
                float v = ((ti[m] == s) ? a[tj[m]] : 0.f) + dq[ti[m]] * L[s][tj[m]];
                s_entbar[e][s][m] = v * sig[m];
            }
        }
    }
    __syncthreads();

    // ---- Eh1 in 2 stages of 8 elements ----
    for (int hstage = 0; hstage < 2; hstage++) {
        {
            const int j = tid;
            float w2row[NTRI];
            #pragma unroll
            for (int m = 0; m < NTRI; m++) w2row[m] = mW2[j * NTRI + m];
            #pragma unroll 2
            for (int el = 0; el < 8; el++) {
                const int e = hstage * 8 + el;
                const float h = (float)s_h2[e][j];
                const float t2 = 1.f - h * h;
                #pragma unroll
                for (int s = 0; s < 4; s++) {
                    float acc = 0.f;
                    #pragma unroll
                    for (int m = 0; m < NTRI; m++) acc += w2row[m] * s_entbar[e][s][m];
                    s_sd[el * 4 + s][j] = (_Float16)(acc * t2);
                }
            }
        }
        __syncthreads();

        phase_eh1(s_sd, W1m_hi, W1m_lo, mW0, s_h1, s_Jp, hstage, wid, fr, fg, kb);
        __syncthreads();
    }

    // ---- finalize per element ----
    if (tid < EPB && (e0 + tid) < n) {
        const int e = tid;
        float q[6], dq[4];
        #pragma unroll
        for (int i = 0; i < 6; i++) q[i] = s_qd[e][i];
        #pragma unroll
        for (int r = 0; r < 4; r++) dq[r] = s_qd[e][6 + r];
        const float x1a = q[2], x1b = q[3], x2a = q[4], x2b = q[5];
        float J[4][6];
        #pragma unroll
        for (int r = 0; r < 4; r++)
            #pragma unroll
            for (int i = 0; i < 6; i++)
                J[r][i] = s_Jp[0][e][r][i] + s_Jp[1][e][r][i] + s_Jp[2][e][r][i] + s_Jp[3][e][r][i];
        float dV[6];
        #pragma unroll
        for (int i = 0; i < 6; i++)
            dV[i] = s_dVp[0][e][i] + s_dVp[1][e][i] + s_dVp[2][e][i] + s_dVp[3][e][i];

        float G[4][4];
        #pragma unroll
        for (int r = 0; r < 4; r++) {
            G[r][0] = J[r][0];
            G[r][1] = J[r][1];
            G[r][2] = -x2a * J[r][2] + x1a * J[r][4];
            G[r][3] = -x2b * J[r][3] + x1b * J[r][5];
        }
        float gL[6];
        #pragma unroll
        for (int i = 0; i < 6; i++) {
            float s = 0.f;
            #pragma unroll
            for (int r = 0; r < 4; r++) s += dq[r] * J[r][i];
            gL[i] = 0.5f * s - dV[i];
        }
        float dLdq[4];
        dLdq[0] = gL[0];
        dLdq[1] = gL[1];
        dLdq[2] = -x2a * gL[2] + x1a * gL[4];
        dLdq[3] = -x2b * gL[3] + x1b * gL[5];
        float b[4];
        #pragma unroll
        for (int r = 0; r < 4; r++) {
            float s = 0.f;
            #pragma unroll
            for (int c = 0; c < 4; c++) s += G[r][c] * dq[c];
            b[r] = dLdq[r] - s;
        }
        float M[4][4];
        #pragma unroll
        for (int r = 0; r < 4; r++)
            #pragma unroll
            for (int c = 0; c <= r; c++) {
                float s = 0.f;
                #pragma unroll
                for (int k = 0; k < 4; k++) s += s_L[e][r * 4 + k] * s_L[e][c * 4 + k];
                M[r][c] = s;
            }
        #pragma unroll
        for (int r = 0; r < 4; r++) M[r][r] += EPS;
        float C00 = sqrtf(M[0][0]);
        float C10 = M[1][0] / C00, C20 = M[2][0] / C00, C30 = M[3][0] / C00;
        float C11 = sqrtf(M[1][1] - C10 * C10);
        float C21 = (M[2][1] - C20 * C10) / C11;
        float C31 = (M[3][1] - C30 * C10) / C11;
        float C22 = sqrtf(M[2][2] - C20 * C20 - C21 * C21);
        float C32 = (M[3][2] - C30 * C20 - C31 * C21) / C22;
        float C33 = sqrtf(M[3][3] - C30 * C30 - C31 * C31 - C32 * C32);
        float y0 = b[0] / C00;
        float y1 = (b[1] - C10 * y0) / C11;
        float y2 = (b[2] - C20 * y0 - C21 * y1) / C22;
        float y3 = (b[3] - C30 * y0 - C31 * y1 - C32 * y2) / C33;
        float d3 = y3 / C33;
        float d2 = (y2 - C32 * d3) / C22;
        float d1 = (y1 - C21 * d2 - C31 * d3) / C11;
        float d0 = (y0 - C10 * d1 - C20 * d2 - C30 * d3) / C00;

        float* o = &out[(e0 + e) * 10];
        o[0] = dq[0];
        o[1] = dq[1];
        o[2] = -x2a * dq[2];
        o[3] = -x2b * dq[3];
        o[4] = x1a * dq[2];
        o[5] = x1b * dq[3];
        o[6] = d0; o[7] = d1; o[8] = d2; o[9] = d3;
    }
}

extern "C" void kernel_launch(void* const* d_in, const int* in_sizes, int n_in,
                              void* d_out, int out_size, void* d_ws, size_t ws_size,
                              hipStream_t stream) {
    const float* x   = (const float*)d_in[0];
    const float* mW0 = (const float*)d_in[1];
    const float* mb0 = (const float*)d_in[2];
    const float* mW1 = (const float*)d_in[3];
    const float* mb1 = (const float*)d_in[4];
    const float* mW2 = (const float*)d_in[5];
    const float* mb2 = (const float*)d_in[6];
    const float* vW0 = (const float*)d_in[7];
    const float* vb0 = (const float*)d_in[8];
    const float* vW1 = (const float*)d_in[9];
    const float* vb1 = (const float*)d_in[10];
    const float* vW2 = (const float*)d_in[11];
    float* out = (float*)d_out;
    const int n = in_sizes[0] / 10;

    prep_kernel<<<H, H, 0, stream>>>(mW1, vW1, mW2, d_ws);

    const int blocks = (n + EPB - 1) / EPB;
    lnn_kernel<<<blocks, 256, 0, stream>>>(x, mW0, mb0, mb1, mW2, mb2,
                                           vW0, vb0, vb1, vW2,
                                           d_ws, out, n);
}